// Round 9
// baseline (74.891 us; speedup 1.0000x reference)
//
#include <hip/hip_runtime.h>
#include <hip/hip_bf16.h>

typedef __attribute__((ext_vector_type(8))) __bf16 bf16x8;
typedef __attribute__((ext_vector_type(4))) float f32x4;

#define B_   64
#define L_   512
#define HID_ 768
#define M_   128
#define R_   64
#define P_   8

// 3-bit XOR swizzle for 64-wide LDS tiles (ushort units, 8-aligned k).
__device__ __forceinline__ int swz(int row, int k, int stride) {
    return row * stride + (k ^ ((row & 7) << 3));
}
// 4-bit XOR swizzle for 128-wide tiles (kills 8-way scattered-write conflicts).
__device__ __forceinline__ int swz4(int row, int k) {
    return row * 128 + (k ^ ((row & 15) << 3));
}

// async 16B global -> LDS (linear dest: wave-uniform base + lane*16)
#define GLL16(gp, lp)                                                        \
    __builtin_amdgcn_global_load_lds(                                        \
        (const __attribute__((address_space(1))) void*)(gp),                 \
        (__attribute__((address_space(3))) void*)(lp), 16, 0, 0)

__device__ __forceinline__ bf16x8 cvt8(float4 f0, float4 f1) {
    bf16x8 v;
    v[0]=(__bf16)f0.x; v[1]=(__bf16)f0.y; v[2]=(__bf16)f0.z; v[3]=(__bf16)f0.w;
    v[4]=(__bf16)f1.x; v[5]=(__bf16)f1.y; v[6]=(__bf16)f1.z; v[7]=(__bf16)f1.w;
    return v;
}

// ---- Kw: transpose+cast proj_W -> Wt, PRE-SWIZZLED per 64-k chunk --------
__global__ __launch_bounds__(256) void k_wt(const float* __restrict__ W,
                                            __bf16* __restrict__ Wt) {
    int idx = blockIdx.x * 256 + threadIdx.x;   // k*128 + n  (coalesced read)
    int k = idx >> 7, n = idx & 127;
    int c = k >> 6, kk = k & 63;
    Wt[c * 8192 + n * 64 + (kk ^ ((n & 7) << 3))] = (__bf16)W[idx];
}

// ---- K_main: proj(64 tokens) -> LDS D -> MaxSim(512 probes) -> pm --------
// Grid dim3(B_, 8), 512 thr (8 waves). GEMM: 4 row-blocks x 2 col-halves.
// Sim: each wave holds 64 probes (4 tiles) in regs, scans the block's 64
// tokens from LDS. D never touches global memory.
__global__ __launch_bounds__(512, 4) void k_projsim(
        const float* __restrict__ hidden, const __bf16* __restrict__ Wt,
        const float* __restrict__ lp, const float* __restrict__ sW,
        const float* __restrict__ oW, const float* __restrict__ dW,
        const int* __restrict__ st, const int* __restrict__ ot,
        const int* __restrict__ sf, const int* __restrict__ ctx,
        const int* __restrict__ btw, float* __restrict__ pm) {
    __shared__ __align__(16) __bf16 Al[2][64 * 64];     // 2 x 8 KB
    __shared__ __align__(16) __bf16 Bl[2][128 * 64];    // 2 x 16 KB
    __shared__ float nbuf[2][64];
    __shared__ float evl[64];
    __shared__ int anyf;
    const int t = threadIdx.x;
    const int lane = t & 63, w = t >> 6;
    const int rlo = lane & 15, g = lane >> 4;
    const int rb = w & 3, ch = w >> 2;      // row-block 0..3, col-half 0..1
    const int b = blockIdx.x, j = blockIdx.y;
    const int row0 = b * L_ + j * 64;

    // evidence inputs (issued early; consumed much later)
    if (t == 0) anyf = 0;
    const int bt = btw[b * L_ + t];               // full-row any() input
    int btww = 0, ctxw = 0;
    if (t < 64) { btww = btw[row0 + t]; ctxw = ctx[row0 + t]; }

    f32x4 acc[4] = {};

    const int ar = t >> 3;            // A stage: row 0..63 (8 threads/row)
    const int ac = (t & 7) * 8;       //          k offset, step 8
    const float* arow = hidden + (size_t)(row0 + ar) * HID_ + ac;

    // ---- prologue: stage chunk 0 into buffer 0 ----
    GLL16(Wt + w * 1024 + lane * 8,       &Bl[0][w * 1024]);
    GLL16(Wt + w * 1024 + 512 + lane * 8, &Bl[0][w * 1024 + 512]);
    {
        float4 f0 = *(const float4*)(arow);
        float4 f1 = *(const float4*)(arow + 4);
        *(bf16x8*)&Al[0][swz(ar, ac, 64)] = cvt8(f0, f1);
    }
    __syncthreads();
    if (bt) anyf = 1;                 // after barrier: t0's anyf=0 is ordered

    // ---- GEMM over 12 k-chunks, 2-phase pipeline ----
    for (int ci = 0; ci < 12; ++ci) {
        const int cur = ci & 1;
        const bool pre = ci < 11;
        float4 f0, f1;
        if (pre) {   // issue next-chunk loads BEFORE compute
            const __bf16* wsrc = Wt + (ci + 1) * 8192 + w * 1024;
            GLL16(wsrc + lane * 8,       &Bl[cur ^ 1][w * 1024]);
            GLL16(wsrc + 512 + lane * 8, &Bl[cur ^ 1][w * 1024 + 512]);
            const float* src = arow + (ci + 1) * 64;
            f0 = *(const float4*)(src);
            f1 = *(const float4*)(src + 4);
        }
#pragma unroll
        for (int s = 0; s < 2; ++s) {
            int kk = s * 32 + g * 8;
            bf16x8 aF = *(const bf16x8*)&Al[cur][swz(rb * 16 + rlo, kk, 64)];
#pragma unroll
            for (int c = 0; c < 4; ++c) {
                bf16x8 bF = *(const bf16x8*)&Bl[cur][swz(ch * 64 + c * 16 + rlo, kk, 64)];
                acc[c] = __builtin_amdgcn_mfma_f32_16x16x32_bf16(aF, bF, acc[c], 0, 0, 0);
            }
        }
        if (pre) {   // write-late: cvt + ds_write after compute
            *(bf16x8*)&Al[cur ^ 1][swz(ar, ac, 64)] = cvt8(f0, f1);
        }
        __syncthreads();
    }

    // ---- norm: partial over this wave's 64 cols, exchange across halves ----
    float ss[4] = {0.f, 0.f, 0.f, 0.f};
#pragma unroll
    for (int c = 0; c < 4; ++c)
#pragma unroll
        for (int r = 0; r < 4; ++r) ss[r] += acc[c][r] * acc[c][r];
#pragma unroll
    for (int r = 0; r < 4; ++r)
#pragma unroll
        for (int off = 1; off < 16; off <<= 1) ss[r] += __shfl_xor(ss[r], off);
    if (rlo == 0) {
#pragma unroll
        for (int r = 0; r < 4; ++r) nbuf[ch][rb * 16 + g * 4 + r] = ss[r];
    }
    __syncthreads();
    float sc[4];
#pragma unroll
    for (int r = 0; r < 4; ++r) {
        float tot = nbuf[0][rb * 16 + g * 4 + r] + nbuf[1][rb * 16 + g * 4 + r];
        sc[r] = 1.0f / fmaxf(sqrtf(tot), 1e-12f);
    }

    // ---- write D chunk (64 tokens x 128 dims, bf16) into LDS (Al reuse) ----
    __bf16* Dl = (__bf16*)Al;      // 16 KB, free after last chunk barrier
#pragma unroll
    for (int c = 0; c < 4; ++c)
#pragma unroll
        for (int r = 0; r < 4; ++r) {
            int row = rb * 16 + g * 4 + r;
            int col = ch * 64 + c * 16 + rlo;
            Dl[swz4(row, col)] = (__bf16)(acc[c][r] * sc[r]);
        }
    const int any = anyf;
    if (t < 64) evl[t] = ((any ? btww : ctxw) != 0) ? 1.0f : 0.0f;
    __syncthreads();               // Dl + evl visible to all waves

    // ---- probe build: this wave's 64 probes (4 tiles), in-register ----
    const int sb = st[b], ob = ot[b], db = sf[b];
    const float* sv = sW + sb * M_;
    const float* ov = oW + ob * M_;
    const float* dv = dW + db * M_;
    bf16x8 qF[4][4];
#pragma unroll
    for (int pt2 = 0; pt2 < 4; ++pt2) {
        const float* lpp = lp + (size_t)(w * 64 + pt2 * 16 + rlo) * M_;
        float qv[32];
        float ssq = 0.f;
#pragma unroll
        for (int ks = 0; ks < 4; ++ks) {
#pragma unroll
            for (int h = 0; h < 2; ++h) {
                const int m0 = ks * 32 + g * 8 + h * 4;
                float4 a  = *(const float4*)(lpp + m0);
                float4 s4 = *(const float4*)(sv + m0);
                float4 o4 = *(const float4*)(ov + m0);
                float4 d4 = *(const float4*)(dv + m0);
                float x0 = a.x + s4.x + o4.x + d4.x;
                float x1 = a.y + s4.y + o4.y + d4.y;
                float x2 = a.z + s4.z + o4.z + d4.z;
                float x3 = a.w + s4.w + o4.w + d4.w;
                qv[ks * 8 + h * 4 + 0] = x0;
                qv[ks * 8 + h * 4 + 1] = x1;
                qv[ks * 8 + h * 4 + 2] = x2;
                qv[ks * 8 + h * 4 + 3] = x3;
                ssq += x0 * x0 + x1 * x1 + x2 * x2 + x3 * x3;
            }
        }
        ssq += __shfl_xor(ssq, 16);
        ssq += __shfl_xor(ssq, 32);
        const float scq = 1.0f / fmaxf(sqrtf(ssq), 1e-12f);
#pragma unroll
        for (int ks = 0; ks < 4; ++ks)
#pragma unroll
            for (int qj = 0; qj < 8; ++qj)
                qF[pt2][ks][qj] = (__bf16)(qv[ks * 8 + qj] * scq);
    }

    // ---- sim: 64 probes x 64 tokens from LDS, masked max ----
    float vmax[4][4];
#pragma unroll
    for (int pt2 = 0; pt2 < 4; ++pt2)
#pragma unroll
        for (int r = 0; r < 4; ++r) vmax[pt2][r] = -1e30f;

#pragma unroll
    for (int tt = 0; tt < 4; ++tt) {
        f32x4 pacc[4] = {};
#pragma unroll
        for (int ks = 0; ks < 4; ++ks) {
            bf16x8 bF = *(const bf16x8*)&Dl[swz4(tt * 16 + rlo, ks * 32 + g * 8)];
            pacc[0] = __builtin_amdgcn_mfma_f32_16x16x32_bf16(qF[0][ks], bF, pacc[0], 0, 0, 0);
            pacc[1] = __builtin_amdgcn_mfma_f32_16x16x32_bf16(qF[1][ks], bF, pacc[1], 0, 0, 0);
            pacc[2] = __builtin_amdgcn_mfma_f32_16x16x32_bf16(qF[2][ks], bF, pacc[2], 0, 0, 0);
            pacc[3] = __builtin_amdgcn_mfma_f32_16x16x32_bf16(qF[3][ks], bF, pacc[3], 0, 0, 0);
        }
        const float e = evl[tt * 16 + rlo];
#pragma unroll
        for (int pt2 = 0; pt2 < 4; ++pt2)
#pragma unroll
            for (int r = 0; r < 4; ++r) {
                float sv2 = (e > 0.5f) ? pacc[pt2][r] : -1e4f;
                vmax[pt2][r] = fmaxf(vmax[pt2][r], sv2);
            }
    }

    // reduce over the 16 token-columns
#pragma unroll
    for (int pt2 = 0; pt2 < 4; ++pt2)
#pragma unroll
        for (int r = 0; r < 4; ++r)
#pragma unroll
            for (int off = 1; off < 16; off <<= 1)
                vmax[pt2][r] = fmaxf(vmax[pt2][r], __shfl_xor(vmax[pt2][r], off));

    if (rlo == 0) {
        float* dst = pm + ((size_t)b * 8 + j) * 512 + w * 64;
#pragma unroll
        for (int pt2 = 0; pt2 < 4; ++pt2)
#pragma unroll
            for (int r = 0; r < 4; ++r)
                dst[pt2 * 16 + g * 4 + r] = vmax[pt2][r];
    }
}

// ---- K_reduce: max over 8 token-chunks, threshold, sum over P=8 ----------
__global__ __launch_bounds__(512) void k_reduce(const float* __restrict__ pm,
                                                float* __restrict__ out) {
    const int b = blockIdx.x, t = threadIdx.x;
    float m = -1e30f;
#pragma unroll
    for (int j = 0; j < 8; ++j)
        m = fmaxf(m, pm[((size_t)b * 8 + j) * 512 + t]);
    m = (m > -1000.0f) ? m : 0.0f;
    m += __shfl_xor(m, 1);
    m += __shfl_xor(m, 2);
    m += __shfl_xor(m, 4);
    if ((t & 7) == 0) out[b * R_ + (t >> 3)] = m;
}

// ---------------- launcher ----------------
extern "C" void kernel_launch(void* const* d_in, const int* in_sizes, int n_in,
                              void* d_out, int out_size, void* d_ws, size_t ws_size,
                              hipStream_t stream) {
    const float* hidden = (const float*)d_in[0];
    const int*   ctx    = (const int*)d_in[1];
    const int*   btw    = (const int*)d_in[2];
    const int*   st     = (const int*)d_in[3];
    const int*   ot     = (const int*)d_in[4];
    const int*   sf     = (const int*)d_in[5];
    const float* W      = (const float*)d_in[6];
    const float* lp     = (const float*)d_in[7];
    const float* sW     = (const float*)d_in[8];
    const float* oW     = (const float*)d_in[9];
    const float* dW     = (const float*)d_in[10];
    float* out = (float*)d_out;

    char* ws = (char*)d_ws;
    __bf16* Wt = (__bf16*)ws;                       // 196608 B (pre-swizzled)
    float*  pm = (float*)(ws + 196608);             // 1 MB partial maxes

    k_wt     <<<(HID_ * M_) / 256, 256, 0, stream>>>(W, Wt);
    k_projsim<<<dim3(B_, 8), 512, 0, stream>>>(hidden, Wt, lp, sW, oW, dW,
                                               st, ot, sf, ctx, btw, pm);
    k_reduce <<<B_, 512, 0, stream>>>(pm, out);
}

// Round 10
// 41.912 us; speedup vs baseline: 1.7869x; 1.7869x over previous
//
#include <hip/hip_runtime.h>
#include <hip/hip_bf16.h>

typedef __attribute__((ext_vector_type(8))) __bf16 bf16x8;
typedef __attribute__((ext_vector_type(4))) float f32x4;

#define B_   64
#define L_   512
#define HID_ 768
#define M_   128
#define R_   64
#define P_   8

// 3-bit XOR swizzle for 64-wide bf16 LDS tiles (ushort units, 8-aligned k).
__device__ __forceinline__ int swz(int row, int k, int stride) {
    return row * stride + (k ^ ((row & 7) << 3));
}
// 4-bit XOR swizzle for 128-wide bf16 tiles (kills 8-way scattered-write conflicts).
__device__ __forceinline__ int swz4(int row, int k) {
    return row * 128 + (k ^ ((row & 15) << 3));
}

// async 16B global -> LDS (linear dest: wave-uniform base + lane*16)
#define GLL16(gp, lp)                                                        \
    __builtin_amdgcn_global_load_lds(                                        \
        (const __attribute__((address_space(1))) void*)(gp),                 \
        (__attribute__((address_space(3))) void*)(lp), 16, 0, 0)

__device__ __forceinline__ bf16x8 cvt8(float4 f0, float4 f1) {
    bf16x8 v;
    v[0]=(__bf16)f0.x; v[1]=(__bf16)f0.y; v[2]=(__bf16)f0.z; v[3]=(__bf16)f0.w;
    v[4]=(__bf16)f1.x; v[5]=(__bf16)f1.y; v[6]=(__bf16)f1.z; v[7]=(__bf16)f1.w;
    return v;
}

// ---- Kw: transpose+cast proj_W -> Wt, PRE-SWIZZLED per 64-k chunk --------
__global__ __launch_bounds__(256) void k_wt(const float* __restrict__ W,
                                            __bf16* __restrict__ Wt) {
    int idx = blockIdx.x * 256 + threadIdx.x;   // k*128 + n  (coalesced read)
    int k = idx >> 7, n = idx & 127;
    int c = k >> 6, kk = k & 63;
    Wt[c * 8192 + n * 64 + (kk ^ ((n & 7) << 3))] = (__bf16)W[idx];
}

// ---- K2: D = l2norm(hidden @ W) -- counted-vmcnt GLL pipeline ------------
// ALL staging via global_load_lds (A as f32, cvt after LDS read).
// Per wave per chunk: 4 GLLs. Steady state: issue next chunk's 4, then
// s_waitcnt vmcnt(4) (current chunk landed, next still in flight) + raw
// s_barrier. No vmcnt(0) drain in the main loop (T3/T4 recipe).
// A f32 tile swizzle: LDS(row, cg) holds global col-group cg^(row&7)
// (4-float groups); inverse applied on the GLL global source address.
// Grid dim3(B_, 8): batch b -> XCD b%8. 512 thr = 4 row-blocks x 2 halves.
// Stores D PRE-SWIZZLED (4-bit): D[row*128 + (col ^ ((row&15)<<3))]
__global__ __launch_bounds__(512, 4) void k_proj(const float* __restrict__ hidden,
                                                 const __bf16* __restrict__ Wt,
                                                 __bf16* __restrict__ D) {
    __shared__ __align__(16) float  Alf[2][64 * 64];    // 2 x 16 KB (tok x k, f32)
    __shared__ __align__(16) __bf16 Bl[2][128 * 64];    // 2 x 16 KB (dim x k, bf16)
    __shared__ float nbuf[2][64];
    const int t = threadIdx.x;
    const int lane = t & 63, w = t >> 6;
    const int rlo = lane & 15, g = lane >> 4;
    const int rb = w & 3, ch = w >> 2;      // row-block 0..3, col-half 0..1
    const int row0 = blockIdx.x * 512 + blockIdx.y * 64;   // b*512 + j*64

    f32x4 acc[4] = {};

    // ---- staging geometry ----
    // A round h (h=0,1): this thread fills LDS linear f32 [ (h*512+t)*4 .. +4 )
    //   row = h*32 + (t>>4), cg = t&15; source col-group = cg ^ (row&7).
    const int sr0 = t >> 4;              // base row within round (0..31)
    const int scg = t & 15;
    const float* hbase = hidden + (size_t)row0 * HID_;

#define STAGE_A(ci_, buf_)                                                     \
    {                                                                          \
        _Pragma("unroll")                                                      \
        for (int h = 0; h < 2; ++h) {                                          \
            const int row = h * 32 + sr0;                                      \
            const int cgs = scg ^ (row & 7);                                   \
            GLL16(hbase + (size_t)row * HID_ + (ci_) * 64 + cgs * 4,           \
                  &Alf[buf_][(h * 8 + w) * 256 + lane * 4]);                   \
        }                                                                      \
    }
#define STAGE_B(ci_, buf_)                                                     \
    {                                                                          \
        const __bf16* wsrc = Wt + (ci_) * 8192 + w * 1024;                     \
        GLL16(wsrc + lane * 8,       &Bl[buf_][w * 1024]);                     \
        GLL16(wsrc + 512 + lane * 8, &Bl[buf_][w * 1024 + 512]);               \
    }

    // ---- prologue: stage chunk 0 ----
    STAGE_A(0, 0);
    STAGE_B(0, 0);

    for (int ci = 0; ci < 12; ++ci) {
        const int cur = ci & 1;
        if (ci < 11) {            // issue next chunk's 4 GLLs (stay in flight)
            STAGE_A(ci + 1, cur ^ 1);
            STAGE_B(ci + 1, cur ^ 1);
            asm volatile("s_waitcnt vmcnt(4)" ::: "memory");
        } else {
            asm volatile("s_waitcnt vmcnt(0)" ::: "memory");
        }
        __builtin_amdgcn_sched_barrier(0);
        __builtin_amdgcn_s_barrier();      // chunk ci ready in LDS, all waves

#pragma unroll
        for (int s = 0; s < 2; ++s) {
            const int row = rb * 16 + rlo;
            const int kkg = s * 8 + g * 2;         // 4-float group index
            const int x = row & 7;
            float4 a0 = *(const float4*)&Alf[cur][row * 64 + ((kkg ^ x) * 4)];
            float4 a1 = *(const float4*)&Alf[cur][row * 64 + (((kkg + 1) ^ x) * 4)];
            bf16x8 aF = cvt8(a0, a1);
            const int kk = s * 32 + g * 8;
#pragma unroll
            for (int c = 0; c < 4; ++c) {
                bf16x8 bF = *(const bf16x8*)&Bl[cur][swz(ch * 64 + c * 16 + rlo, kk, 64)];
                acc[c] = __builtin_amdgcn_mfma_f32_16x16x32_bf16(aF, bF, acc[c], 0, 0, 0);
            }
        }
        __builtin_amdgcn_s_barrier();      // all waves done reading buf[cur]
    }
#undef STAGE_A
#undef STAGE_B

    // ---- norm: partial over this wave's 64 cols, exchange across halves ----
    float ss[4] = {0.f, 0.f, 0.f, 0.f};
#pragma unroll
    for (int c = 0; c < 4; ++c)
#pragma unroll
        for (int r = 0; r < 4; ++r) ss[r] += acc[c][r] * acc[c][r];
#pragma unroll
    for (int r = 0; r < 4; ++r)
#pragma unroll
        for (int off = 1; off < 16; off <<= 1) ss[r] += __shfl_xor(ss[r], off);
    if (rlo == 0) {
#pragma unroll
        for (int r = 0; r < 4; ++r) nbuf[ch][rb * 16 + g * 4 + r] = ss[r];
    }
    __syncthreads();
    float sc[4];
#pragma unroll
    for (int r = 0; r < 4; ++r) {
        float tot = nbuf[0][rb * 16 + g * 4 + r] + nbuf[1][rb * 16 + g * 4 + r];
        sc[r] = 1.0f / fmaxf(sqrtf(tot), 1e-12f);
    }

    // ---- repack into LDS (4-bit pre-swizzle), then coalesced vector store ----
    __bf16* Dst = (__bf16*)Alf;    // 16 KB, free after last chunk barrier
#pragma unroll
    for (int c = 0; c < 4; ++c)
#pragma unroll
        for (int r = 0; r < 4; ++r) {
            int row = rb * 16 + g * 4 + r;
            int col = ch * 64 + c * 16 + rlo;
            Dst[swz4(row, col)] = (__bf16)(acc[c][r] * sc[r]);
        }
    __syncthreads();
#pragma unroll
    for (int h = 0; h < 2; ++h) {
        int row = (t >> 4) + h * 32;
        int seg = t & 15;
        bf16x8 v = *(const bf16x8*)&Dst[row * 128 + seg * 8];
        *(bf16x8*)(D + (size_t)(row0 + row) * M_ + seg * 8) = v;
    }
}

// ---- K3: fused probes + evidence + sim + masked max + sum -> logits ------
// (R7 version verbatim: grid dim3(B_,4), LDS-staged D, 2-probe-tile reuse.)
__global__ __launch_bounds__(256) void k_sim(const float* __restrict__ lp,
                                             const float* __restrict__ sW,
                                             const float* __restrict__ oW,
                                             const float* __restrict__ dW,
                                             const int* __restrict__ st,
                                             const int* __restrict__ ot,
                                             const int* __restrict__ sf,
                                             const int* __restrict__ ctx,
                                             const int* __restrict__ btw,
                                             const __bf16* __restrict__ D,
                                             float* __restrict__ out) {
    __shared__ __align__(16) __bf16 Dl[2][128 * 128];   // 2 x 32 KB
    __shared__ float evl[L_];
    __shared__ int anyf;
    const int t = threadIdx.x;
    const int lane = t & 63, w = t >> 6;
    const int rlo = lane & 15, g = lane >> 4;
    const int b = blockIdx.x, pt = blockIdx.y;

    const __bf16* Db = D + (size_t)b * L_ * M_;

    // ---- issue chunk-0 DMA first (overlaps probe build) ----
#pragma unroll
    for (int q = 0; q < 8; ++q)
        GLL16(Db + q * 2048 + w * 512 + lane * 8, &Dl[0][q * 2048 + w * 512]);

    // ---- evidence (fused) ----
    if (t == 0) anyf = 0;
    __syncthreads();
    int v0 = btw[b * L_ + t], v1 = btw[b * L_ + t + 256];
    int c0 = ctx[b * L_ + t], c1 = ctx[b * L_ + t + 256];
    if (v0 | v1) anyf = 1;          // benign race: all writers store 1
    __syncthreads();
    const int any = anyf;
    evl[t]       = (any ? v0 : c0) ? 1.0f : 0.0f;
    evl[t + 256] = (any ? v1 : c1) ? 1.0f : 0.0f;

    // ---- probe build: 2 tiles per wave, in-register ----
    const int sb = st[b], ob = ot[b], db = sf[b];
    const float* sv = sW + sb * M_;
    const float* ov = oW + ob * M_;
    const float* dv = dW + db * M_;
    bf16x8 qF[2][4];
#pragma unroll
    for (int pt2 = 0; pt2 < 2; ++pt2) {
        const float* lpp = lp + (size_t)(pt * 128 + w * 32 + pt2 * 16 + rlo) * M_;
        float qv[32];
        float ssq = 0.f;
#pragma unroll
        for (int ks = 0; ks < 4; ++ks) {
#pragma unroll
            for (int h = 0; h < 2; ++h) {
                const int m0 = ks * 32 + g * 8 + h * 4;
                float4 a  = *(const float4*)(lpp + m0);
                float4 s4 = *(const float4*)(sv + m0);
                float4 o4 = *(const float4*)(ov + m0);
                float4 d4 = *(const float4*)(dv + m0);
                float x0 = a.x + s4.x + o4.x + d4.x;
                float x1 = a.y + s4.y + o4.y + d4.y;
                float x2 = a.z + s4.z + o4.z + d4.z;
                float x3 = a.w + s4.w + o4.w + d4.w;
                qv[ks * 8 + h * 4 + 0] = x0;
                qv[ks * 8 + h * 4 + 1] = x1;
                qv[ks * 8 + h * 4 + 2] = x2;
                qv[ks * 8 + h * 4 + 3] = x3;
                ssq += x0 * x0 + x1 * x1 + x2 * x2 + x3 * x3;
            }
        }
        ssq += __shfl_xor(ssq, 16);
        ssq += __shfl_xor(ssq, 32);
        const float scq = 1.0f / fmaxf(sqrtf(ssq), 1e-12f);
#pragma unroll
        for (int ks = 0; ks < 4; ++ks)
#pragma unroll
            for (int j = 0; j < 8; ++j)
                qF[pt2][ks][j] = (__bf16)(qv[ks * 8 + j] * scq);
    }

    __syncthreads();   // Dl[0] + evl ready

    // ---- MaxSim main loop: 1 barrier/chunk, DMA next while computing ----
    float vmax[2][4];
#pragma unroll
    for (int pt2 = 0; pt2 < 2; ++pt2)
#pragma unroll
        for (int r = 0; r < 4; ++r) vmax[pt2][r] = -1e30f;

    for (int tc = 0; tc < 4; ++tc) {
        const int cur = tc & 1;
        if (tc < 3) {
#pragma unroll
            for (int q = 0; q < 8; ++q)
                GLL16(Db + (tc + 1) * 16384 + q * 2048 + w * 512 + lane * 8,
                      &Dl[cur ^ 1][q * 2048 + w * 512]);
        }
#pragma unroll
        for (int tt = 0; tt < 8; ++tt) {
            f32x4 pacc[2] = {};
#pragma unroll
            for (int ks = 0; ks < 4; ++ks) {
                bf16x8 bF = *(const bf16x8*)&Dl[cur][swz4(tt * 16 + rlo, ks * 32 + g * 8)];
                pacc[0] = __builtin_amdgcn_mfma_f32_16x16x32_bf16(qF[0][ks], bF, pacc[0], 0, 0, 0);
                pacc[1] = __builtin_amdgcn_mfma_f32_16x16x32_bf16(qF[1][ks], bF, pacc[1], 0, 0, 0);
            }
            const float e = evl[tc * 128 + tt * 16 + rlo];
#pragma unroll
            for (int pt2 = 0; pt2 < 2; ++pt2)
#pragma unroll
                for (int r = 0; r < 4; ++r) {
                    float sv2 = (e > 0.5f) ? pacc[pt2][r] : -1e4f;
                    vmax[pt2][r] = fmaxf(vmax[pt2][r], sv2);
                }
        }
        __syncthreads();
    }

    // max over the 16 token-columns held across the 16-lane group
#pragma unroll
    for (int pt2 = 0; pt2 < 2; ++pt2)
#pragma unroll
        for (int r = 0; r < 4; ++r)
#pragma unroll
            for (int off = 1; off < 16; off <<= 1)
                vmax[pt2][r] = fmaxf(vmax[pt2][r], __shfl_xor(vmax[pt2][r], off));

#pragma unroll
    for (int pt2 = 0; pt2 < 2; ++pt2) {
        float psum = 0.f;
#pragma unroll
        for (int r = 0; r < 4; ++r)
            psum += (vmax[pt2][r] > -1000.0f) ? vmax[pt2][r] : 0.0f;
        float rtot = psum + __shfl_xor(psum, 16);
        if ((lane & 31) == 0) {
            int rr = pt * 16 + w * 4 + pt2 * 2 + (g >> 1);
            out[b * R_ + rr] = rtot;
        }
    }
}

// ---------------- launcher ----------------
extern "C" void kernel_launch(void* const* d_in, const int* in_sizes, int n_in,
                              void* d_out, int out_size, void* d_ws, size_t ws_size,
                              hipStream_t stream) {
    const float* hidden = (const float*)d_in[0];
    const int*   ctx    = (const int*)d_in[1];
    const int*   btw    = (const int*)d_in[2];
    const int*   st     = (const int*)d_in[3];
    const int*   ot     = (const int*)d_in[4];
    const int*   sf     = (const int*)d_in[5];
    const float* W      = (const float*)d_in[6];
    const float* lp     = (const float*)d_in[7];
    const float* sW     = (const float*)d_in[8];
    const float* oW     = (const float*)d_in[9];
    const float* dW     = (const float*)d_in[10];
    float* out = (float*)d_out;

    char* ws = (char*)d_ws;
    __bf16* Wt = (__bf16*)ws;                       // 196608 B (pre-swizzled)
    __bf16* D  = (__bf16*)(ws + 196608);            // 8 MB (pre-swizzled 4-bit)

    k_wt  <<<(HID_ * M_) / 256, 256, 0, stream>>>(W, Wt);
    k_proj<<<dim3(B_, 8), 512, 0, stream>>>(hidden, Wt, D);
    k_sim <<<dim3(B_, 4), 256, 0, stream>>>(lp, sW, oW, dW, st, ot, sf, ctx, btw, D, out);
}